// Round 12
// baseline (295.458 us; speedup 1.0000x reference)
//
#include <hip/hip_runtime.h>
#include <math.h>

typedef __attribute__((ext_vector_type(4))) float f32x4;
typedef __attribute__((ext_vector_type(8))) short s16x8;

__device__ __forceinline__ short f2bf_rne(float f) {
  unsigned u = __float_as_uint(f);
  unsigned r = u + 0x7FFFu + ((u >> 16) & 1u);
  return (short)(r >> 16);
}
__device__ __forceinline__ float bf2f(short b) {
  return __uint_as_float(((unsigned)(unsigned short)b) << 16);
}

#define WAIT_VMCNT(N) asm volatile("s_waitcnt vmcnt(" #N ")" ::: "memory")
#define WAIT_LGKM0()  asm volatile("s_waitcnt lgkmcnt(0)" ::: "memory")
#define BAR()         __builtin_amdgcn_s_barrier()

__device__ __forceinline__ void gl_lds16(const void* g, void* l) {
  __builtin_amdgcn_global_load_lds(
      (const __attribute__((address_space(1))) void*)g,
      (__attribute__((address_space(3))) void*)l, 16, 0, 0);
}

// ---------------- W1 -> bf16 hi/lo fragment pre-pack (verified r7-r11) ----------------
// frag element j of lane l holds k = chunk*32 + (l>>4)*8 + j, col = nt*16 + (l&15)
// ws layout: slot = (chunk*4 + nt)*2 + sel (0=hi,1=lo); frag addr = (slot*64 + l)*8 ushorts
__global__ __launch_bounds__(256) void prep_w1(const float* __restrict__ W1,
                                               unsigned short* __restrict__ wf) {
  const int c   = blockIdx.x;         // k-chunk 0..39
  const int l   = threadIdx.x & 63;
  const int nt  = threadIdx.x >> 6;   // 0..3
  const int kb  = c * 32 + (l >> 4) * 8;
  const int col = nt * 16 + (l & 15);
  s16x8 hi, lo;
#pragma unroll
  for (int j = 0; j < 8; ++j) {
    float f = W1[(kb + j) * 64 + col];
    short h = f2bf_rne(f);
    hi[j] = h;
    lo[j] = f2bf_rne(f - bf2f(h));
  }
  const int slot = (c * 4 + nt) * 2;
  *(s16x8*)(wf + (size_t)(slot * 64 + l) * 8)       = hi;
  *(s16x8*)(wf + (size_t)((slot + 1) * 64 + l) * 8) = lo;
}

// ---------------- circuit macros (verified rounds 1-11) ----------------
#define APPLY_RY(BIT, C, S)                                                  \
  { _Pragma("unroll")                                                        \
    for (int i = 0; i < 16; ++i) {                                           \
      if (!(i & (BIT))) {                                                    \
        const int j = i | (BIT);                                             \
        float ar = re[i], ai = im[i], br = re[j], bi = im[j];                \
        re[i] = fmaf((C), ar, -(S) * br);                                    \
        im[i] = fmaf((C), ai, -(S) * bi);                                    \
        re[j] = fmaf((S), ar, (C) * br);                                     \
        im[j] = fmaf((S), ai, (C) * bi);                                     \
      }                                                                      \
    } }

#define APPLY_RZ(BIT, C, S)                                                  \
  { _Pragma("unroll")                                                        \
    for (int i = 0; i < 16; ++i) {                                           \
      float vr = re[i], vi = im[i];                                          \
      if (!(i & (BIT))) { re[i] = fmaf((C), vr, (S) * vi);                   \
                          im[i] = fmaf((C), vi, -(S) * vr); }                \
      else              { re[i] = fmaf((C), vr, -(S) * vi);                  \
                          im[i] = fmaf((C), vi, (S) * vr); }                 \
    } }

#define APPLY_CNOT(CB, TB)                                                   \
  { _Pragma("unroll")                                                        \
    for (int i = 0; i < 16; ++i) {                                           \
      if ((i & (CB)) && !(i & (TB))) {                                       \
        const int j = i | (TB);                                              \
        float t = re[i]; re[i] = re[j]; re[j] = t;                           \
        t = im[i]; im[i] = im[j]; im[j] = t;                                 \
      }                                                                      \
    } }

// Shared tail: reduced[4] -> statevector -> head -> logit
__device__ __forceinline__ float qfc_head(
    const float* __restrict__ red, const float* __restrict__ qw,
    const float* __restrict__ Wc1, const float* __restrict__ bc1,
    const float* __restrict__ Wc2, const float* __restrict__ bc2) {
  float re[16], im[16];
#pragma unroll
  for (int i = 0; i < 16; ++i) { re[i] = 0.f; im[i] = 0.f; }
  re[0] = 1.f;
  {
    float s0, c0; sincosf(0.5f * red[0], &s0, &c0); APPLY_RY(8, c0, s0);
    float s1, c1; sincosf(0.5f * red[1], &s1, &c1); APPLY_RY(4, c1, s1);
    float s2, c2; sincosf(0.5f * red[2], &s2, &c2); APPLY_RY(2, c2, s2);
    float s3, c3; sincosf(0.5f * red[3], &s3, &c3); APPLY_RY(1, c3, s3);
  }
  for (int lyr = 0; lyr < 3; ++lyr) {
    const float* ql = qw + lyr * 8;
    { float sn, cn; sincosf(0.5f * ql[0], &sn, &cn); APPLY_RY(8, cn, sn); }
    { float sn, cn; sincosf(0.5f * ql[1], &sn, &cn); APPLY_RZ(8, cn, sn); }
    { float sn, cn; sincosf(0.5f * ql[2], &sn, &cn); APPLY_RY(4, cn, sn); }
    { float sn, cn; sincosf(0.5f * ql[3], &sn, &cn); APPLY_RZ(4, cn, sn); }
    { float sn, cn; sincosf(0.5f * ql[4], &sn, &cn); APPLY_RY(2, cn, sn); }
    { float sn, cn; sincosf(0.5f * ql[5], &sn, &cn); APPLY_RZ(2, cn, sn); }
    { float sn, cn; sincosf(0.5f * ql[6], &sn, &cn); APPLY_RY(1, cn, sn); }
    { float sn, cn; sincosf(0.5f * ql[7], &sn, &cn); APPLY_RZ(1, cn, sn); }
    APPLY_CNOT(8, 4);
    APPLY_CNOT(4, 2);
    APPLY_CNOT(2, 1);
    APPLY_CNOT(1, 8);
  }
  float q0 = 0.f, q1 = 0.f, q2 = 0.f, q3 = 0.f;
#pragma unroll
  for (int i = 0; i < 16; ++i) {
    const float pr = fmaf(re[i], re[i], im[i] * im[i]);
    q0 += (i & 8) ? -pr : pr;
    q1 += (i & 4) ? -pr : pr;
    q2 += (i & 2) ? -pr : pr;
    q3 += (i & 1) ? -pr : pr;
  }
  float logit = bc2[0];
#pragma unroll
  for (int j = 0; j < 16; ++j) {
    float a = bc1[j];
    a = fmaf(red[0], Wc1[j],       a);
    a = fmaf(red[1], Wc1[16 + j],  a);
    a = fmaf(red[2], Wc1[32 + j],  a);
    a = fmaf(red[3], Wc1[48 + j],  a);
    a = fmaf(q0,     Wc1[64 + j],  a);
    a = fmaf(q1,     Wc1[80 + j],  a);
    a = fmaf(q2,     Wc1[96 + j],  a);
    a = fmaf(q3,     Wc1[112 + j], a);
    logit = fmaf(fmaxf(a, 0.f), Wc2[j], logit);
  }
  return logit;
}

// ============ split-K(5) GEMM + in-kernel finisher ============
// 1280 blocks x 256 thr: block = (rt 0..255: 64 rows) x (kq 0..4: 8 chunks of K=32).
// Wave w owns rows rt*64+w*16..+16; all 4 waves share each staged B chunk.
// LDS exactly 32KB (B dbuf 2x8KB + A dbuf 2x8KB) -> 5 blocks/CU = 20 waves/CU.
// A tile XOR-swizzled (T21: pre-swizzled global source + swizzled read).
// After partial store: threadfence + per-rt atomic counter; 5th block sums and
// runs the fused tail (deterministic: fixed sum order, single writer).
__global__ __launch_bounds__(256) void qfc_gemm5(
    const float* __restrict__ x,            // [16384,1280]
    const unsigned short* __restrict__ wf,  // W1 frags (prep_w1)
    float* __restrict__ pw,                 // partials [1280][4096]
    int* __restrict__ cnt,                  // [256] arrival counters (zeroed/call)
    const float* __restrict__ b1, const float* __restrict__ W2,
    const float* __restrict__ b2, const float* __restrict__ qw,
    const float* __restrict__ Wc1, const float* __restrict__ bc1,
    const float* __restrict__ Wc2, const float* __restrict__ bc2,
    float* __restrict__ out) {
  __shared__ s16x8 Bs[2][512];     // 2 x 8KB, shared B frags (hi/lo)
  __shared__ float As[2][4][512];  // 2 bufs x 4 waves x 2KB, swizzled A

  const int tid  = threadIdx.x;
  const int l    = tid & 63;
  const int wv   = tid >> 6;
  const int bid  = blockIdx.x;
  const int rt   = bid / 5;        // row tile
  const int kq   = bid - rt * 5;   // k fifth (8 chunks)
  const int r0   = rt * 64;
  const int arow = l & 15;
  const int kg   = l >> 4;         // 0..3

  // ---- A staging source (pre-swizzled: LDS unit u <-> row=u>>3, kp=(u&7)^(row&7)) ----
  const int u0 = l, u1 = l + 64;
  const int row0 = u0 >> 3, kp0 = (u0 & 7) ^ (row0 & 7);
  const int row1 = u1 >> 3, kp1 = (u1 & 7) ^ (row1 & 7);
  const float* xs0 = x + (size_t)(r0 + wv * 16 + row0) * 1280 + kq * 256 + kp0 * 4;
  const float* xs1 = x + (size_t)(r0 + wv * 16 + row1) * 1280 + kq * 256 + kp1 * 4;
  // B source: this kq's 8 chunks contiguous in wf
  const s16x8* wfb = (const s16x8*)wf + (size_t)(kq * 8) * 512 + wv * 128 + l;

  // compute-side swizzled A read offsets (floats)
  const int aoff0 = (arow * 8 + ((kg * 2)     ^ (arow & 7))) * 4;
  const int aoff1 = (arow * 8 + ((kg * 2 + 1) ^ (arow & 7))) * 4;

  f32x4 acc[4];
#pragma unroll
  for (int nt = 0; nt < 4; ++nt) acc[nt] = (f32x4)(0.f);

  // per thread per chunk: 2 B-gloads + 2 A-gloads, all 16B
#define STAGE(C, BUF)                                                        \
  {                                                                          \
    const s16x8* bsrc_ = wfb + (size_t)(C) * 512;                            \
    gl_lds16(bsrc_,      &Bs[BUF][wv * 128]);                                \
    gl_lds16(bsrc_ + 64, &Bs[BUF][wv * 128 + 64]);                           \
    gl_lds16(xs0 + (C) * 32, &As[BUF][wv][0]);                               \
    gl_lds16(xs1 + (C) * 32, &As[BUF][wv][256]);                             \
  }

  STAGE(0, 0)
  STAGE(1, 1)

#pragma unroll
  for (int c = 0; c < 8; ++c) {
    const int buf = c & 1;
    // chunk c's 4 per-wave loads done; chunk c+1's 4 stay in flight
    if (c < 7) { WAIT_VMCNT(4); } else { WAIT_VMCNT(0); }
    BAR();  // all waves' pieces of chunk c landed

    // ---- A piece (row arow, k kg*8..+8), swizzled read, convert hi/lo ----
    const float* Ab = &As[buf][wv][0];
    const float4 fa = *(const float4*)(Ab + aoff0);
    const float4 fb = *(const float4*)(Ab + aoff1);
    float f[8] = {fa.x, fa.y, fa.z, fa.w, fb.x, fb.y, fb.z, fb.w};
    s16x8 ah, al;
#pragma unroll
    for (int j = 0; j < 8; ++j) {
      short h = f2bf_rne(f[j]);
      ah[j] = h;
      al[j] = (short)(__float_as_uint(f[j] - bf2f(h)) >> 16);  // trunc ok for lo
    }
    // ---- shared B frags ----
    s16x8 bq[8];
#pragma unroll
    for (int q = 0; q < 8; ++q) bq[q] = Bs[buf][q * 64 + l];

    WAIT_LGKM0();  // this wave's reads of buf complete
    if (c + 2 < 8) {
      BAR();                 // all waves done reading buf -> safe to restage
      STAGE(c + 2, buf)      // loads fly during the MFMAs below
    }

    // 12 MFMA: xh*wh + xl*wh + xh*wl (same order as r7-r11 -> same numerics)
#pragma unroll
    for (int nt = 0; nt < 4; ++nt)
      acc[nt] = __builtin_amdgcn_mfma_f32_16x16x32_bf16(ah, bq[nt * 2], acc[nt], 0, 0, 0);
#pragma unroll
    for (int nt = 0; nt < 4; ++nt)
      acc[nt] = __builtin_amdgcn_mfma_f32_16x16x32_bf16(al, bq[nt * 2], acc[nt], 0, 0, 0);
#pragma unroll
    for (int nt = 0; nt < 4; ++nt)
      acc[nt] = __builtin_amdgcn_mfma_f32_16x16x32_bf16(ah, bq[nt * 2 + 1], acc[nt], 0, 0, 0);
  }
#undef STAGE

  // ---- store partial: D row_local = kg*4+q, col = nt*16+arow (m89 C/D map) ----
  float* wsp = pw + (size_t)bid * 4096;
#pragma unroll
  for (int nt = 0; nt < 4; ++nt)
    *(float4*)(wsp + (nt * 16 + arow) * 64 + wv * 16 + kg * 4) =
        make_float4(acc[nt][0], acc[nt][1], acc[nt][2], acc[nt][3]);

  // ---- arrival protocol: 5th block for this rt becomes the finisher ----
  __threadfence();     // make this thread's partial stores device-visible
  __syncthreads();     // all threads' fences done before the atomic
  int pred = 0;
  if (tid == 0) pred = (atomicAdd(&cnt[rt], 1) == 4);
  if (__syncthreads_count(pred) == 0) return;  // not last -> done
  __threadfence();     // acquire side: partials of all 5 blocks now visible

  // ================= finisher tail (256 thr: 4 per sample x 64) =================
  const int s  = tid >> 2;  // sample 0..63
  const int cq = tid & 3;   // c-quarter (16 cols)
  const float* pb = pw + (size_t)rt * 5 * 4096;

  float h4[4] = {0.f, 0.f, 0.f, 0.f};
#pragma unroll
  for (int cc = 0; cc < 16; ++cc) {
    const int c = cq * 16 + cc;
    const int o = c * 64 + s;
    float p = pb[o];
#pragma unroll
    for (int q = 1; q < 5; ++q) p += pb[q * 4096 + o];  // fixed order: deterministic
    float hv = fmaxf(p + b1[c], 0.f);
    const float4 w2 = *(const float4*)(W2 + c * 4);
    h4[0] = fmaf(hv, w2.x, h4[0]);
    h4[1] = fmaf(hv, w2.y, h4[1]);
    h4[2] = fmaf(hv, w2.z, h4[2]);
    h4[3] = fmaf(hv, w2.w, h4[3]);
  }
#pragma unroll
  for (int k = 0; k < 4; ++k) {
    h4[k] += __shfl_xor(h4[k], 1);
    h4[k] += __shfl_xor(h4[k], 2);
  }

  float red[4];
#pragma unroll
  for (int k = 0; k < 4; ++k) red[k] = tanhf(h4[k] + b2[k]);

  const float logit = qfc_head(red, qw, Wc1, bc1, Wc2, bc2);
  if (cq == 0) out[r0 + s] = logit;
}

// ============ Fallback: round-1 pure-VALU kernel (no ws needed) ============
#define NKT 20
__global__ __launch_bounds__(256) void qfc_fused(
    const float* __restrict__ x, const float* __restrict__ W1,
    const float* __restrict__ b1, const float* __restrict__ W2,
    const float* __restrict__ b2, const float* __restrict__ qw,
    const float* __restrict__ Wc1, const float* __restrict__ bc1,
    const float* __restrict__ Wc2, const float* __restrict__ bc2,
    float* __restrict__ out) {
  __shared__ float lds[16384];
  const int tid = threadIdx.x;
  const int lane = tid & 63;
  const int wv = tid >> 6;
  const int rg = lane >> 3;
  const int cg = lane & 7;
  const int r0 = blockIdx.x * 64;
  float acc[8][8];
#pragma unroll
  for (int i = 0; i < 8; ++i)
#pragma unroll
    for (int j = 0; j < 8; ++j) acc[i][j] = 0.f;
  const float* xrow = x + (size_t)(r0 + lane) * 1280 + wv * 16;
  const int aBase = wv * 1024;
  const int bBase = 8192 + wv * 1024;
  float4 a_st[4], b_st[4];
  auto issue_loads = [&](int kt) {
    const float* ap = xrow + kt * 64;
#pragma unroll
    for (int i = 0; i < 4; ++i) a_st[i] = *(const float4*)(ap + i * 4);
    const float* bp = W1 + kt * 4096 + wv * 1024 + lane * 4;
#pragma unroll
    for (int i = 0; i < 4; ++i) b_st[i] = *(const float4*)(bp + i * 256);
  };
  auto write_stage = [&](int buf) {
    float* A = &lds[buf * 4096 + aBase];
#pragma unroll
    for (int i = 0; i < 4; ++i) {
      float* p = A + i * 256 + lane;
      p[0] = a_st[i].x; p[64] = a_st[i].y; p[128] = a_st[i].z; p[192] = a_st[i].w;
    }
    float* Bp = &lds[buf * 4096 + bBase + lane * 4];
#pragma unroll
    for (int i = 0; i < 4; ++i) *(float4*)(Bp + i * 256) = b_st[i];
  };
  auto compute_tile = [&](int buf) {
#pragma unroll
    for (int m = 0; m < 16; ++m) {
      const float* Ak = &lds[buf * 4096 + aBase + m * 64];
      const float* Bk = &lds[buf * 4096 + bBase + m * 64];
      const float4 a0 = *(const float4*)(Ak + rg * 8);
      const float4 a1 = *(const float4*)(Ak + rg * 8 + 4);
      const float4 c0 = *(const float4*)(Bk + cg * 8);
      const float4 c1 = *(const float4*)(Bk + cg * 8 + 4);
      const float av[8] = {a0.x, a0.y, a0.z, a0.w, a1.x, a1.y, a1.z, a1.w};
      const float bv[8] = {c0.x, c0.y, c0.z, c0.w, c1.x, c1.y, c1.z, c1.w};
#pragma unroll
      for (int i = 0; i < 8; ++i)
#pragma unroll
        for (int j = 0; j < 8; ++j) acc[i][j] = fmaf(av[i], bv[j], acc[i][j]);
    }
  };
  issue_loads(0);
  write_stage(0);
  for (int kt = 0; kt < NKT; ++kt) {
    const int buf = kt & 1;
    if (kt + 1 < NKT) issue_loads(kt + 1);
    compute_tile(buf);
    if (kt + 1 < NKT) write_stage(buf ^ 1);
  }
  __syncthreads();
#pragma unroll
  for (int j = 0; j < 8; ++j) {
    const int c = cg * 8 + j;
    float* p = &lds[wv * 4096 + c * 64 + rg * 8];
    *(float4*)p = make_float4(acc[0][j], acc[1][j], acc[2][j], acc[3][j]);
    *(float4*)(p + 4) = make_float4(acc[4][j], acc[5][j], acc[6][j], acc[7][j]);
  }
  __syncthreads();
  const int s = tid >> 2;
  const int cq = tid & 3;
  float h4[4] = {0.f, 0.f, 0.f, 0.f};
#pragma unroll
  for (int cc = 0; cc < 16; ++cc) {
    const int c = cq * 16 + cc;
    const int o = c * 64 + s;
    float pp = (lds[o] + lds[4096 + o]) + (lds[8192 + o] + lds[12288 + o]);
    float hv = fmaxf(pp + b1[c], 0.f);
    const float4 w2 = *(const float4*)(W2 + c * 4);
    h4[0] = fmaf(hv, w2.x, h4[0]);
    h4[1] = fmaf(hv, w2.y, h4[1]);
    h4[2] = fmaf(hv, w2.z, h4[2]);
    h4[3] = fmaf(hv, w2.w, h4[3]);
  }
#pragma unroll
  for (int k = 0; k < 4; ++k) {
    h4[k] += __shfl_xor(h4[k], 1);
    h4[k] += __shfl_xor(h4[k], 2);
  }
  float red[4];
#pragma unroll
  for (int k = 0; k < 4; ++k) red[k] = tanhf(h4[k] + b2[k]);
  const float logit = qfc_head(red, qw, Wc1, bc1, Wc2, bc2);
  if (cq == 0) out[r0 + s] = logit;
}

extern "C" void kernel_launch(void* const* d_in, const int* in_sizes, int n_in,
                              void* d_out, int out_size, void* d_ws, size_t ws_size,
                              hipStream_t stream) {
  const float* x   = (const float*)d_in[0];
  const float* W1  = (const float*)d_in[1];
  const float* b1  = (const float*)d_in[2];
  const float* W2  = (const float*)d_in[3];
  const float* b2  = (const float*)d_in[4];
  const float* qw  = (const float*)d_in[5];
  const float* Wc1 = (const float*)d_in[6];
  const float* bc1 = (const float*)d_in[7];
  const float* Wc2 = (const float*)d_in[8];
  const float* bc2 = (const float*)d_in[9];

  const size_t WF_BYTES  = 327680;                     // W1 hi/lo frags
  const size_t CNT_OFF   = WF_BYTES;                   // 256 ints
  const size_t PW_OFF    = WF_BYTES + 4096;            // 16B-aligned
  const size_t PW_BYTES  = (size_t)1280 * 4096 * 4;    // 20 MB partials
  if (ws_size >= PW_OFF + PW_BYTES) {
    unsigned short* wf = (unsigned short*)d_ws;
    int*   cnt = (int*)((char*)d_ws + CNT_OFF);
    float* pw  = (float*)((char*)d_ws + PW_OFF);
    hipMemsetAsync(cnt, 0, 256 * sizeof(int), stream);  // graph-capturable node
    prep_w1<<<dim3(40), dim3(256), 0, stream>>>(W1, wf);
    qfc_gemm5<<<dim3(1280), dim3(256), 0, stream>>>(
        x, wf, pw, cnt, b1, W2, b2, qw, Wc1, bc1, Wc2, bc2, (float*)d_out);
  } else {
    qfc_fused<<<dim3(256), dim3(256), 0, stream>>>(
        x, W1, b1, W2, b2, qw, Wc1, bc1, Wc2, bc2, (float*)d_out);
  }
}

// Round 13
// 40.658 us; speedup vs baseline: 7.2669x; 7.2669x over previous
//
#include <hip/hip_runtime.h>
#include <math.h>

typedef __attribute__((ext_vector_type(4))) float f32x4;
typedef __attribute__((ext_vector_type(8))) short s16x8;

__device__ __forceinline__ short f2bf_rne(float f) {
  unsigned u = __float_as_uint(f);
  unsigned r = u + 0x7FFFu + ((u >> 16) & 1u);
  return (short)(r >> 16);
}
__device__ __forceinline__ float bf2f(short b) {
  return __uint_as_float(((unsigned)(unsigned short)b) << 16);
}

#define WAIT_VMCNT(N) asm volatile("s_waitcnt vmcnt(" #N ")" ::: "memory")
#define BAR()         __builtin_amdgcn_s_barrier()
#define CFENCE()      asm volatile("" ::: "memory")
#define SCHEDB()      __builtin_amdgcn_sched_barrier(0)

__device__ __forceinline__ void gl_lds16(const void* g, void* l) {
  __builtin_amdgcn_global_load_lds(
      (const __attribute__((address_space(1))) void*)g,
      (__attribute__((address_space(3))) void*)l, 16, 0, 0);
}

// pinned 16B global load to named VGPRs (cannot be sunk/reordered by compiler;
// completion is covered by our manual vmcnt accounting)
#define GLOAD4(D, P) \
  asm volatile("global_load_dwordx4 %0, %1, off" : "=&v"(D) : "v"(P))

// ---------------- W1 -> bf16 hi/lo fragment pre-pack (verified r7-r12) ----------------
// frag element j of lane l holds k = chunk*32 + (l>>4)*8 + j, col = nt*16 + (l&15)
// ws layout: slot = (chunk*4 + nt)*2 + sel (0=hi,1=lo); frag addr = (slot*64 + l)*8 ushorts
__global__ __launch_bounds__(256) void prep_w1(const float* __restrict__ W1,
                                               unsigned short* __restrict__ wf) {
  const int c   = blockIdx.x;         // k-chunk 0..39
  const int l   = threadIdx.x & 63;
  const int nt  = threadIdx.x >> 6;   // 0..3
  const int kb  = c * 32 + (l >> 4) * 8;
  const int col = nt * 16 + (l & 15);
  s16x8 hi, lo;
#pragma unroll
  for (int j = 0; j < 8; ++j) {
    float f = W1[(kb + j) * 64 + col];
    short h = f2bf_rne(f);
    hi[j] = h;
    lo[j] = f2bf_rne(f - bf2f(h));
  }
  const int slot = (c * 4 + nt) * 2;
  *(s16x8*)(wf + (size_t)(slot * 64 + l) * 8)       = hi;
  *(s16x8*)(wf + (size_t)((slot + 1) * 64 + l) * 8) = lo;
}

// ---------------- circuit macros (verified rounds 1-12) ----------------
#define APPLY_RY(BIT, C, S)                                                  \
  { _Pragma("unroll")                                                        \
    for (int i = 0; i < 16; ++i) {                                           \
      if (!(i & (BIT))) {                                                    \
        const int j = i | (BIT);                                             \
        float ar = re[i], ai = im[i], br = re[j], bi = im[j];                \
        re[i] = fmaf((C), ar, -(S) * br);                                    \
        im[i] = fmaf((C), ai, -(S) * bi);                                    \
        re[j] = fmaf((S), ar, (C) * br);                                     \
        im[j] = fmaf((S), ai, (C) * bi);                                     \
      }                                                                      \
    } }

#define APPLY_RZ(BIT, C, S)                                                  \
  { _Pragma("unroll")                                                        \
    for (int i = 0; i < 16; ++i) {                                           \
      float vr = re[i], vi = im[i];                                          \
      if (!(i & (BIT))) { re[i] = fmaf((C), vr, (S) * vi);                   \
                          im[i] = fmaf((C), vi, -(S) * vr); }                \
      else              { re[i] = fmaf((C), vr, -(S) * vi);                  \
                          im[i] = fmaf((C), vi, (S) * vr); }                 \
    } }

#define APPLY_CNOT(CB, TB)                                                   \
  { _Pragma("unroll")                                                        \
    for (int i = 0; i < 16; ++i) {                                           \
      if ((i & (CB)) && !(i & (TB))) {                                       \
        const int j = i | (TB);                                              \
        float t = re[i]; re[i] = re[j]; re[j] = t;                           \
        t = im[i]; im[i] = im[j]; im[j] = t;                                 \
      }                                                                      \
    } }

// Shared tail: reduced[4] -> statevector -> head -> logit
__device__ __forceinline__ float qfc_head(
    const float* __restrict__ red, const float* __restrict__ qw,
    const float* __restrict__ Wc1, const float* __restrict__ bc1,
    const float* __restrict__ Wc2, const float* __restrict__ bc2) {
  float re[16], im[16];
#pragma unroll
  for (int i = 0; i < 16; ++i) { re[i] = 0.f; im[i] = 0.f; }
  re[0] = 1.f;
  {
    float s0, c0; sincosf(0.5f * red[0], &s0, &c0); APPLY_RY(8, c0, s0);
    float s1, c1; sincosf(0.5f * red[1], &s1, &c1); APPLY_RY(4, c1, s1);
    float s2, c2; sincosf(0.5f * red[2], &s2, &c2); APPLY_RY(2, c2, s2);
    float s3, c3; sincosf(0.5f * red[3], &s3, &c3); APPLY_RY(1, c3, s3);
  }
  for (int lyr = 0; lyr < 3; ++lyr) {
    const float* ql = qw + lyr * 8;
    { float sn, cn; sincosf(0.5f * ql[0], &sn, &cn); APPLY_RY(8, cn, sn); }
    { float sn, cn; sincosf(0.5f * ql[1], &sn, &cn); APPLY_RZ(8, cn, sn); }
    { float sn, cn; sincosf(0.5f * ql[2], &sn, &cn); APPLY_RY(4, cn, sn); }
    { float sn, cn; sincosf(0.5f * ql[3], &sn, &cn); APPLY_RZ(4, cn, sn); }
    { float sn, cn; sincosf(0.5f * ql[4], &sn, &cn); APPLY_RY(2, cn, sn); }
    { float sn, cn; sincosf(0.5f * ql[5], &sn, &cn); APPLY_RZ(2, cn, sn); }
    { float sn, cn; sincosf(0.5f * ql[6], &sn, &cn); APPLY_RY(1, cn, sn); }
    { float sn, cn; sincosf(0.5f * ql[7], &sn, &cn); APPLY_RZ(1, cn, sn); }
    APPLY_CNOT(8, 4);
    APPLY_CNOT(4, 2);
    APPLY_CNOT(2, 1);
    APPLY_CNOT(1, 8);
  }
  float q0 = 0.f, q1 = 0.f, q2 = 0.f, q3 = 0.f;
#pragma unroll
  for (int i = 0; i < 16; ++i) {
    const float pr = fmaf(re[i], re[i], im[i] * im[i]);
    q0 += (i & 8) ? -pr : pr;
    q1 += (i & 4) ? -pr : pr;
    q2 += (i & 2) ? -pr : pr;
    q3 += (i & 1) ? -pr : pr;
  }
  float logit = bc2[0];
#pragma unroll
  for (int j = 0; j < 16; ++j) {
    float a = bc1[j];
    a = fmaf(red[0], Wc1[j],       a);
    a = fmaf(red[1], Wc1[16 + j],  a);
    a = fmaf(red[2], Wc1[32 + j],  a);
    a = fmaf(red[3], Wc1[48 + j],  a);
    a = fmaf(q0,     Wc1[64 + j],  a);
    a = fmaf(q1,     Wc1[80 + j],  a);
    a = fmaf(q2,     Wc1[96 + j],  a);
    a = fmaf(q3,     Wc1[112 + j], a);
    logit = fmaf(fmaxf(a, 0.f), Wc2[j], logit);
  }
  return logit;
}

// ============ Kernel A: split-K(5) GEMM, B-only LDS, A in registers ============
// 1280 blocks x 256 thr: block = (rt: 64 rows) x (kq 0..4: 8 chunks of K=32).
// Wave w owns rows rt*64+w*16..+16; 4 waves cooperatively stage+share each B chunk.
// LDS = 3 bufs x 8KB = 24KB -> 5 blocks/CU (20 waves/CU), grid = one full round.
// ONE barrier per chunk (3-buf rotation); steady-state vmcnt(4); A via pinned
// asm global_load_dwordx4 into a 3-set register rotation (compiler cannot sink).
// NO fences/atomics (r12 lesson) -- partials combined by a separate kernel.
__global__ __launch_bounds__(256) void qfc_gemm(
    const float* __restrict__ x,            // [16384,1280]
    const unsigned short* __restrict__ wf,  // W1 frags (prep_w1)
    float* __restrict__ pw)                 // partials [1280][4096]
{
  __shared__ s16x8 Bs[3][512];  // 3 x 8KB B frag buffers (hi/lo)

  const int tid  = threadIdx.x;
  const int l    = tid & 63;
  const int wv   = tid >> 6;
  const int bid  = blockIdx.x;
  const int rt   = bid / 5;        // row tile
  const int kq   = bid - rt * 5;   // k fifth (8 chunks of K=32)
  const int r0   = rt * 64;
  const int arow = l & 15;
  const int kg   = l >> 4;         // 0..3

  // A source: lane handles row r0+wv*16+arow, k slice kq*256 + c*32 + kg*8
  const float* xrow = x + (size_t)(r0 + wv * 16 + arow) * 1280 + kq * 256 + kg * 8;
  // B source: this kq's 8 chunks contiguous in wf; this wave stages slice wv*128
  const s16x8* wfb = (const s16x8*)wf + (size_t)(kq * 8) * 512 + wv * 128 + l;

  f32x4 acc[4];
#pragma unroll
  for (int nt = 0; nt < 4; ++nt) acc[nt] = (f32x4)(0.f);

  float4 a00, a01, a10, a11, a20, a21;  // 3-set A rotation (set = c%3)

  // ---- prologue: issue order [B0, A0, B1, A1] = 8 vmem ops in flight ----
  gl_lds16(wfb,      &Bs[0][wv * 128]);
  gl_lds16(wfb + 64, &Bs[0][wv * 128 + 64]);
  GLOAD4(a00, xrow);
  GLOAD4(a01, xrow + 4);
  gl_lds16(wfb + 512,      &Bs[1][wv * 128]);
  gl_lds16(wfb + 512 + 64, &Bs[1][wv * 128 + 64]);
  GLOAD4(a10, xrow + 32);
  GLOAD4(a11, xrow + 36);

  // Per chunk C: vmcnt(4) -> B(C)+A(C) landed (4 newer stay in flight); barrier
  // (all waves' B slices present); restage buf (C+2)%3 (last read at C-1, whose
  // ds_reads completed before each wave reached this barrier); cvt A; 12 MFMA.
#define CHUNK(C, AC0, AC1, AN0, AN1)                                          \
  {                                                                           \
    if ((C) < 7) { WAIT_VMCNT(4); } else { WAIT_VMCNT(0); }                   \
    BAR();                                                                    \
    CFENCE();                                                                 \
    SCHEDB();                                                                 \
    if ((C) + 2 < 8) {                                                        \
      const s16x8* bsrc_ = wfb + (size_t)((C) + 2) * 512;                     \
      gl_lds16(bsrc_,      &Bs[((C) + 2) % 3][wv * 128]);                     \
      gl_lds16(bsrc_ + 64, &Bs[((C) + 2) % 3][wv * 128 + 64]);                \
      GLOAD4(AN0, xrow + ((C) + 2) * 32);                                     \
      GLOAD4(AN1, xrow + ((C) + 2) * 32 + 4);                                 \
    }                                                                         \
    SCHEDB();                                                                 \
    float f_[8] = {AC0.x, AC0.y, AC0.z, AC0.w, AC1.x, AC1.y, AC1.z, AC1.w};   \
    s16x8 ah_, al_;                                                           \
    _Pragma("unroll")                                                         \
    for (int j = 0; j < 8; ++j) {                                             \
      short h_ = f2bf_rne(f_[j]);                                             \
      ah_[j] = h_;                                                            \
      al_[j] = (short)(__float_as_uint(f_[j] - bf2f(h_)) >> 16);              \
    }                                                                         \
    _Pragma("unroll")                                                         \
    for (int nt = 0; nt < 4; ++nt) {                                          \
      s16x8 bh_ = Bs[(C) % 3][(nt * 2) * 64 + l];                             \
      s16x8 bl_ = Bs[(C) % 3][(nt * 2 + 1) * 64 + l];                         \
      acc[nt] = __builtin_amdgcn_mfma_f32_16x16x32_bf16(ah_, bh_, acc[nt], 0, 0, 0); \
      acc[nt] = __builtin_amdgcn_mfma_f32_16x16x32_bf16(al_, bh_, acc[nt], 0, 0, 0); \
      acc[nt] = __builtin_amdgcn_mfma_f32_16x16x32_bf16(ah_, bl_, acc[nt], 0, 0, 0); \
    }                                                                         \
  }

  CHUNK(0, a00, a01, a20, a21)
  CHUNK(1, a10, a11, a00, a01)
  CHUNK(2, a20, a21, a10, a11)
  CHUNK(3, a00, a01, a20, a21)
  CHUNK(4, a10, a11, a00, a01)
  CHUNK(5, a20, a21, a10, a11)
  CHUNK(6, a00, a01, a20, a21)
  CHUNK(7, a10, a11, a00, a01)
#undef CHUNK

  // ---- store partial: D row_local = kg*4+q, col = nt*16+arow (m89 C/D map) ----
  float* wsp = pw + (size_t)bid * 4096;
#pragma unroll
  for (int nt = 0; nt < 4; ++nt)
    *(float4*)(wsp + (nt * 16 + arow) * 64 + wv * 16 + kg * 4) =
        make_float4(acc[nt][0], acc[nt][1], acc[nt][2], acc[nt][3]);
}

// ============ Kernel B: combine 5 partials + fused tail (r9-proven) ============
// 256 blocks x 256 threads; block rt covers samples rt*64..+64, 4 threads/sample.
__global__ __launch_bounds__(256) void qfc_tail(
    const float* __restrict__ pw,   // partials [1280][4096], 5 per rt
    const float* __restrict__ b1, const float* __restrict__ W2,
    const float* __restrict__ b2, const float* __restrict__ qw,
    const float* __restrict__ Wc1, const float* __restrict__ bc1,
    const float* __restrict__ Wc2, const float* __restrict__ bc2,
    float* __restrict__ out) {
  const int tid = threadIdx.x;
  const int s   = tid >> 2;  // sample within tile 0..63
  const int cq  = tid & 3;   // c-quarter (16 cols)
  const int rt  = blockIdx.x;
  const float* pb = pw + (size_t)rt * 5 * 4096;

  float h4[4] = {0.f, 0.f, 0.f, 0.f};
#pragma unroll
  for (int cc = 0; cc < 16; ++cc) {
    const int c = cq * 16 + cc;
    const int o = c * 64 + s;
    float p = pb[o];
#pragma unroll
    for (int q = 1; q < 5; ++q) p += pb[q * 4096 + o];  // fixed order
    float hv = fmaxf(p + b1[c], 0.f);
    const float4 w2 = *(const float4*)(W2 + c * 4);
    h4[0] = fmaf(hv, w2.x, h4[0]);
    h4[1] = fmaf(hv, w2.y, h4[1]);
    h4[2] = fmaf(hv, w2.z, h4[2]);
    h4[3] = fmaf(hv, w2.w, h4[3]);
  }
#pragma unroll
  for (int k = 0; k < 4; ++k) {
    h4[k] += __shfl_xor(h4[k], 1);
    h4[k] += __shfl_xor(h4[k], 2);
  }

  float red[4];
#pragma unroll
  for (int k = 0; k < 4; ++k) red[k] = tanhf(h4[k] + b2[k]);

  const float logit = qfc_head(red, qw, Wc1, bc1, Wc2, bc2);
  if (cq == 0) out[rt * 64 + s] = logit;
}

// ============ Fallback: round-1 pure-VALU kernel (no ws needed) ============
#define NKT 20
__global__ __launch_bounds__(256) void qfc_fused(
    const float* __restrict__ x, const float* __restrict__ W1,
    const float* __restrict__ b1, const float* __restrict__ W2,
    const float* __restrict__ b2, const float* __restrict__ qw,
    const float* __restrict__ Wc1, const float* __restrict__ bc1,
    const float* __restrict__ Wc2, const float* __restrict__ bc2,
    float* __restrict__ out) {
  __shared__ float lds[16384];
  const int tid = threadIdx.x;
  const int lane = tid & 63;
  const int wv = tid >> 6;
  const int rg = lane >> 3;
  const int cg = lane & 7;
  const int r0 = blockIdx.x * 64;
  float acc[8][8];
#pragma unroll
  for (int i = 0; i < 8; ++i)
#pragma unroll
    for (int j = 0; j < 8; ++j) acc[i][j] = 0.f;
  const float* xrow = x + (size_t)(r0 + lane) * 1280 + wv * 16;
  const int aBase = wv * 1024;
  const int bBase = 8192 + wv * 1024;
  float4 a_st[4], b_st[4];
  auto issue_loads = [&](int kt) {
    const float* ap = xrow + kt * 64;
#pragma unroll
    for (int i = 0; i < 4; ++i) a_st[i] = *(const float4*)(ap + i * 4);
    const float* bp = W1 + kt * 4096 + wv * 1024 + lane * 4;
#pragma unroll
    for (int i = 0; i < 4; ++i) b_st[i] = *(const float4*)(bp + i * 256);
  };
  auto write_stage = [&](int buf) {
    float* A = &lds[buf * 4096 + aBase];
#pragma unroll
    for (int i = 0; i < 4; ++i) {
      float* p = A + i * 256 + lane;
      p[0] = a_st[i].x; p[64] = a_st[i].y; p[128] = a_st[i].z; p[192] = a_st[i].w;
    }
    float* Bp = &lds[buf * 4096 + bBase + lane * 4];
#pragma unroll
    for (int i = 0; i < 4; ++i) *(float4*)(Bp + i * 256) = b_st[i];
  };
  auto compute_tile = [&](int buf) {
#pragma unroll
    for (int m = 0; m < 16; ++m) {
      const float* Ak = &lds[buf * 4096 + aBase + m * 64];
      const float* Bk = &lds[buf * 4096 + bBase + m * 64];
      const float4 a0 = *(const float4*)(Ak + rg * 8);
      const float4 a1 = *(const float4*)(Ak + rg * 8 + 4);
      const float4 c0 = *(const float4*)(Bk + cg * 8);
      const float4 c1 = *(const float4*)(Bk + cg * 8 + 4);
      const float av[8] = {a0.x, a0.y, a0.z, a0.w, a1.x, a1.y, a1.z, a1.w};
      const float bv[8] = {c0.x, c0.y, c0.z, c0.w, c1.x, c1.y, c1.z, c1.w};
#pragma unroll
      for (int i = 0; i < 8; ++i)
#pragma unroll
        for (int j = 0; j < 8; ++j) acc[i][j] = fmaf(av[i], bv[j], acc[i][j]);
    }
  };
  issue_loads(0);
  write_stage(0);
  for (int kt = 0; kt < NKT; ++kt) {
    const int buf = kt & 1;
    if (kt + 1 < NKT) issue_loads(kt + 1);
    compute_tile(buf);
    if (kt + 1 < NKT) write_stage(buf ^ 1);
  }
  __syncthreads();
#pragma unroll
  for (int j = 0; j < 8; ++j) {
    const int c = cg * 8 + j;
    float* p = &lds[wv * 4096 + c * 64 + rg * 8];
    *(float4*)p = make_float4(acc[0][j], acc[1][j], acc[2][j], acc[3][j]);
    *(float4*)(p + 4) = make_float4(acc[4][j], acc[5][j], acc[6][j], acc[7][j]);
  }
  __syncthreads();
  const int s = tid >> 2;
  const int cq = tid & 3;
  float h4[4] = {0.f, 0.f, 0.f, 0.f};
#pragma unroll
  for (int cc = 0; cc < 16; ++cc) {
    const int c = cq * 16 + cc;
    const int o = c * 64 + s;
    float pp = (lds[o] + lds[4096 + o]) + (lds[8192 + o] + lds[12288 + o]);
    float hv = fmaxf(pp + b1[c], 0.f);
    const float4 w2 = *(const float4*)(W2 + c * 4);
    h4[0] = fmaf(hv, w2.x, h4[0]);
    h4[1] = fmaf(hv, w2.y, h4[1]);
    h4[2] = fmaf(hv, w2.z, h4[2]);
    h4[3] = fmaf(hv, w2.w, h4[3]);
  }
#pragma unroll
  for (int k = 0; k < 4; ++k) {
    h4[k] += __shfl_xor(h4[k], 1);
    h4[k] += __shfl_xor(h4[k], 2);
  }
  float red[4];
#pragma unroll
  for (int k = 0; k < 4; ++k) red[k] = tanhf(h4[k] + b2[k]);
  const float logit = qfc_head(red, qw, Wc1, bc1, Wc2, bc2);
  if (cq == 0) out[r0 + s] = logit;
}

extern "C" void kernel_launch(void* const* d_in, const int* in_sizes, int n_in,
                              void* d_out, int out_size, void* d_ws, size_t ws_size,
                              hipStream_t stream) {
  const float* x   = (const float*)d_in[0];
  const float* W1  = (const float*)d_in[1];
  const float* b1  = (const float*)d_in[2];
  const float* W2  = (const float*)d_in[3];
  const float* b2  = (const float*)d_in[4];
  const float* qw  = (const float*)d_in[5];
  const float* Wc1 = (const float*)d_in[6];
  const float* bc1 = (const float*)d_in[7];
  const float* Wc2 = (const float*)d_in[8];
  const float* bc2 = (const float*)d_in[9];

  const size_t WF_BYTES = 327680;                    // W1 hi/lo frags
  const size_t PW_OFF   = WF_BYTES;
  const size_t PW_BYTES = (size_t)1280 * 4096 * 4;   // 20 MB partials
  if (ws_size >= PW_OFF + PW_BYTES) {
    unsigned short* wf = (unsigned short*)d_ws;
    float* pw = (float*)((char*)d_ws + PW_OFF);
    prep_w1<<<dim3(40), dim3(256), 0, stream>>>(W1, wf);
    qfc_gemm<<<dim3(1280), dim3(256), 0, stream>>>(x, wf, pw);
    qfc_tail<<<dim3(256), dim3(256), 0, stream>>>(
        pw, b1, W2, b2, qw, Wc1, bc1, Wc2, bc2, (float*)d_out);
  } else {
    qfc_fused<<<dim3(256), dim3(256), 0, stream>>>(
        x, W1, b1, W2, b2, qw, Wc1, bc1, Wc2, bc2, (float*)d_out);
  }
}

// Round 14
// 40.132 us; speedup vs baseline: 7.3622x; 1.0131x over previous
//
#include <hip/hip_runtime.h>
#include <math.h>

typedef __attribute__((ext_vector_type(4))) float f32x4;
typedef __attribute__((ext_vector_type(8))) short s16x8;

__device__ __forceinline__ short f2bf_rne(float f) {
  unsigned u = __float_as_uint(f);
  unsigned r = u + 0x7FFFu + ((u >> 16) & 1u);
  return (short)(r >> 16);
}
__device__ __forceinline__ float bf2f(short b) {
  return __uint_as_float(((unsigned)(unsigned short)b) << 16);
}

#define WAIT_VMCNT(N) asm volatile("s_waitcnt vmcnt(" #N ")" ::: "memory")
#define BAR()         __builtin_amdgcn_s_barrier()
#define CFENCE()      asm volatile("" ::: "memory")
#define SCHEDB()      __builtin_amdgcn_sched_barrier(0)

__device__ __forceinline__ void gl_lds16(const void* g, void* l) {
  __builtin_amdgcn_global_load_lds(
      (const __attribute__((address_space(1))) void*)g,
      (__attribute__((address_space(3))) void*)l, 16, 0, 0);
}

// pinned 16B global load to named VGPRs (cannot be sunk/reordered by compiler;
// completion is covered by our manual vmcnt accounting)
#define GLOAD4(D, P) \
  asm volatile("global_load_dwordx4 %0, %1, off" : "=&v"(D) : "v"(P))

// ---------------- W1 -> bf16 hi/lo fragment pre-pack (verified r7-r12) ----------------
// frag element j of lane l holds k = chunk*32 + (l>>4)*8 + j, col = nt*16 + (l&15)
// ws layout: slot = (chunk*4 + nt)*2 + sel (0=hi,1=lo); frag addr = (slot*64 + l)*8 ushorts
__global__ __launch_bounds__(256) void prep_w1(const float* __restrict__ W1,
                                               unsigned short* __restrict__ wf) {
  const int c   = blockIdx.x;         // k-chunk 0..39
  const int l   = threadIdx.x & 63;
  const int nt  = threadIdx.x >> 6;   // 0..3
  const int kb  = c * 32 + (l >> 4) * 8;
  const int col = nt * 16 + (l & 15);
  s16x8 hi, lo;
#pragma unroll
  for (int j = 0; j < 8; ++j) {
    float f = W1[(kb + j) * 64 + col];
    short h = f2bf_rne(f);
    hi[j] = h;
    lo[j] = f2bf_rne(f - bf2f(h));
  }
  const int slot = (c * 4 + nt) * 2;
  *(s16x8*)(wf + (size_t)(slot * 64 + l) * 8)       = hi;
  *(s16x8*)(wf + (size_t)((slot + 1) * 64 + l) * 8) = lo;
}

// ---------------- circuit macros (verified rounds 1-12) ----------------
#define APPLY_RY(BIT, C, S)                                                  \
  { _Pragma("unroll")                                                        \
    for (int i = 0; i < 16; ++i) {                                           \
      if (!(i & (BIT))) {                                                    \
        const int j = i | (BIT);                                             \
        float ar = re[i], ai = im[i], br = re[j], bi = im[j];                \
        re[i] = fmaf((C), ar, -(S) * br);                                    \
        im[i] = fmaf((C), ai, -(S) * bi);                                    \
        re[j] = fmaf((S), ar, (C) * br);                                     \
        im[j] = fmaf((S), ai, (C) * bi);                                     \
      }                                                                      \
    } }

#define APPLY_RZ(BIT, C, S)                                                  \
  { _Pragma("unroll")                                                        \
    for (int i = 0; i < 16; ++i) {                                           \
      float vr = re[i], vi = im[i];                                          \
      if (!(i & (BIT))) { re[i] = fmaf((C), vr, (S) * vi);                   \
                          im[i] = fmaf((C), vi, -(S) * vr); }                \
      else              { re[i] = fmaf((C), vr, -(S) * vi);                  \
                          im[i] = fmaf((C), vi, (S) * vr); }                 \
    } }

#define APPLY_CNOT(CB, TB)                                                   \
  { _Pragma("unroll")                                                        \
    for (int i = 0; i < 16; ++i) {                                           \
      if ((i & (CB)) && !(i & (TB))) {                                       \
        const int j = i | (TB);                                              \
        float t = re[i]; re[i] = re[j]; re[j] = t;                           \
        t = im[i]; im[i] = im[j]; im[j] = t;                                 \
      }                                                                      \
    } }

// Shared tail: reduced[4] -> statevector -> head -> logit
__device__ __forceinline__ float qfc_head(
    const float* __restrict__ red, const float* __restrict__ qw,
    const float* __restrict__ Wc1, const float* __restrict__ bc1,
    const float* __restrict__ Wc2, const float* __restrict__ bc2) {
  float re[16], im[16];
#pragma unroll
  for (int i = 0; i < 16; ++i) { re[i] = 0.f; im[i] = 0.f; }
  re[0] = 1.f;
  {
    float s0, c0; sincosf(0.5f * red[0], &s0, &c0); APPLY_RY(8, c0, s0);
    float s1, c1; sincosf(0.5f * red[1], &s1, &c1); APPLY_RY(4, c1, s1);
    float s2, c2; sincosf(0.5f * red[2], &s2, &c2); APPLY_RY(2, c2, s2);
    float s3, c3; sincosf(0.5f * red[3], &s3, &c3); APPLY_RY(1, c3, s3);
  }
  for (int lyr = 0; lyr < 3; ++lyr) {
    const float* ql = qw + lyr * 8;
    { float sn, cn; sincosf(0.5f * ql[0], &sn, &cn); APPLY_RY(8, cn, sn); }
    { float sn, cn; sincosf(0.5f * ql[1], &sn, &cn); APPLY_RZ(8, cn, sn); }
    { float sn, cn; sincosf(0.5f * ql[2], &sn, &cn); APPLY_RY(4, cn, sn); }
    { float sn, cn; sincosf(0.5f * ql[3], &sn, &cn); APPLY_RZ(4, cn, sn); }
    { float sn, cn; sincosf(0.5f * ql[4], &sn, &cn); APPLY_RY(2, cn, sn); }
    { float sn, cn; sincosf(0.5f * ql[5], &sn, &cn); APPLY_RZ(2, cn, sn); }
    { float sn, cn; sincosf(0.5f * ql[6], &sn, &cn); APPLY_RY(1, cn, sn); }
    { float sn, cn; sincosf(0.5f * ql[7], &sn, &cn); APPLY_RZ(1, cn, sn); }
    APPLY_CNOT(8, 4);
    APPLY_CNOT(4, 2);
    APPLY_CNOT(2, 1);
    APPLY_CNOT(1, 8);
  }
  float q0 = 0.f, q1 = 0.f, q2 = 0.f, q3 = 0.f;
#pragma unroll
  for (int i = 0; i < 16; ++i) {
    const float pr = fmaf(re[i], re[i], im[i] * im[i]);
    q0 += (i & 8) ? -pr : pr;
    q1 += (i & 4) ? -pr : pr;
    q2 += (i & 2) ? -pr : pr;
    q3 += (i & 1) ? -pr : pr;
  }
  float logit = bc2[0];
#pragma unroll
  for (int j = 0; j < 16; ++j) {
    float a = bc1[j];
    a = fmaf(red[0], Wc1[j],       a);
    a = fmaf(red[1], Wc1[16 + j],  a);
    a = fmaf(red[2], Wc1[32 + j],  a);
    a = fmaf(red[3], Wc1[48 + j],  a);
    a = fmaf(q0,     Wc1[64 + j],  a);
    a = fmaf(q1,     Wc1[80 + j],  a);
    a = fmaf(q2,     Wc1[96 + j],  a);
    a = fmaf(q3,     Wc1[112 + j], a);
    logit = fmaf(fmaxf(a, 0.f), Wc2[j], logit);
  }
  return logit;
}

// ============ Kernel A: split-K(5) GEMM, B-only LDS, A in registers ============
// 1280 blocks x 256 thr: block = (rt: 64 rows) x (kq 0..4: 8 chunks of K=32).
// Wave w owns rows rt*64+w*16..+16; 4 waves cooperatively stage+share each B chunk.
// LDS = 3 bufs x 8KB = 24KB -> 5 blocks/CU (20 waves/CU), grid = one full round.
// ONE barrier per chunk (3-buf rotation); steady-state vmcnt(4); A via pinned
// asm global_load_dwordx4 into a 3-set register rotation (compiler cannot sink).
// NO fences/atomics (r12 lesson) -- partials combined by a separate kernel.
__global__ __launch_bounds__(256) void qfc_gemm(
    const float* __restrict__ x,            // [16384,1280]
    const unsigned short* __restrict__ wf,  // W1 frags (prep_w1)
    float* __restrict__ pw)                 // partials [1280][4096]
{
  __shared__ s16x8 Bs[3][512];  // 3 x 8KB B frag buffers (hi/lo)

  const int tid  = threadIdx.x;
  const int l    = tid & 63;
  const int wv   = tid >> 6;
  const int bid  = blockIdx.x;
  const int rt   = bid / 5;        // row tile
  const int kq   = bid - rt * 5;   // k fifth (8 chunks of K=32)
  const int r0   = rt * 64;
  const int arow = l & 15;
  const int kg   = l >> 4;         // 0..3

  // A source: lane handles row r0+wv*16+arow, k slice kq*256 + c*32 + kg*8
  const float* xrow = x + (size_t)(r0 + wv * 16 + arow) * 1280 + kq * 256 + kg * 8;
  // B source: this kq's 8 chunks contiguous in wf; this wave stages slice wv*128
  const s16x8* wfb = (const s16x8*)wf + (size_t)(kq * 8) * 512 + wv * 128 + l;

  f32x4 acc[4];
#pragma unroll
  for (int nt = 0; nt < 4; ++nt) acc[nt] = (f32x4)(0.f);

  float4 a00, a01, a10, a11, a20, a21;  // 3-set A rotation (set = c%3)

  // ---- prologue: issue order [B0, A0, B1, A1] = 8 vmem ops in flight ----
  gl_lds16(wfb,      &Bs[0][wv * 128]);
  gl_lds16(wfb + 64, &Bs[0][wv * 128 + 64]);
  GLOAD4(a00, xrow);
  GLOAD4(a01, xrow + 4);
  gl_lds16(wfb + 512,      &Bs[1][wv * 128]);
  gl_lds16(wfb + 512 + 64, &Bs[1][wv * 128 + 64]);
  GLOAD4(a10, xrow + 32);
  GLOAD4(a11, xrow + 36);

  // Per chunk C: vmcnt(4) -> B(C)+A(C) landed (4 newer stay in flight); barrier
  // (all waves' B slices present); restage buf (C+2)%3 (last read at C-1, whose
  // ds_reads completed before each wave reached this barrier); cvt A; 12 MFMA.
#define CHUNK(C, AC0, AC1, AN0, AN1)                                          \
  {                                                                           \
    if ((C) < 7) { WAIT_VMCNT(4); } else { WAIT_VMCNT(0); }                   \
    BAR();                                                                    \
    CFENCE();                                                                 \
    SCHEDB();                                                                 \
    if ((C) + 2 < 8) {                                                        \
      const s16x8* bsrc_ = wfb + (size_t)((C) + 2) * 512;                     \
      gl_lds16(bsrc_,      &Bs[((C) + 2) % 3][wv * 128]);                     \
      gl_lds16(bsrc_ + 64, &Bs[((C) + 2) % 3][wv * 128 + 64]);                \
      GLOAD4(AN0, xrow + ((C) + 2) * 32);                                     \
      GLOAD4(AN1, xrow + ((C) + 2) * 32 + 4);                                 \
    }                                                                         \
    SCHEDB();                                                                 \
    float f_[8] = {AC0.x, AC0.y, AC0.z, AC0.w, AC1.x, AC1.y, AC1.z, AC1.w};   \
    s16x8 ah_, al_;                                                           \
    _Pragma("unroll")                                                         \
    for (int j = 0; j < 8; ++j) {                                             \
      short h_ = f2bf_rne(f_[j]);                                             \
      ah_[j] = h_;                                                            \
      al_[j] = (short)(__float_as_uint(f_[j] - bf2f(h_)) >> 16);              \
    }                                                                         \
    _Pragma("unroll")                                                         \
    for (int nt = 0; nt < 4; ++nt) {                                          \
      s16x8 bh_ = Bs[(C) % 3][(nt * 2) * 64 + l];                             \
      s16x8 bl_ = Bs[(C) % 3][(nt * 2 + 1) * 64 + l];                         \
      acc[nt] = __builtin_amdgcn_mfma_f32_16x16x32_bf16(ah_, bh_, acc[nt], 0, 0, 0); \
      acc[nt] = __builtin_amdgcn_mfma_f32_16x16x32_bf16(al_, bh_, acc[nt], 0, 0, 0); \
      acc[nt] = __builtin_amdgcn_mfma_f32_16x16x32_bf16(ah_, bl_, acc[nt], 0, 0, 0); \
    }                                                                         \
  }

  CHUNK(0, a00, a01, a20, a21)
  CHUNK(1, a10, a11, a00, a01)
  CHUNK(2, a20, a21, a10, a11)
  CHUNK(3, a00, a01, a20, a21)
  CHUNK(4, a10, a11, a00, a01)
  CHUNK(5, a20, a21, a10, a11)
  CHUNK(6, a00, a01, a20, a21)
  CHUNK(7, a10, a11, a00, a01)
#undef CHUNK

  // ---- store partial: D row_local = kg*4+q, col = nt*16+arow (m89 C/D map) ----
  float* wsp = pw + (size_t)bid * 4096;
#pragma unroll
  for (int nt = 0; nt < 4; ++nt)
    *(float4*)(wsp + (nt * 16 + arow) * 64 + wv * 16 + kg * 4) =
        make_float4(acc[nt][0], acc[nt][1], acc[nt][2], acc[nt][3]);
}

// ============ Kernel B: combine 5 partials + fused tail (r9-proven) ============
// 256 blocks x 256 threads; block rt covers samples rt*64..+64, 4 threads/sample.
__global__ __launch_bounds__(256) void qfc_tail(
    const float* __restrict__ pw,   // partials [1280][4096], 5 per rt
    const float* __restrict__ b1, const float* __restrict__ W2,
    const float* __restrict__ b2, const float* __restrict__ qw,
    const float* __restrict__ Wc1, const float* __restrict__ bc1,
    const float* __restrict__ Wc2, const float* __restrict__ bc2,
    float* __restrict__ out) {
  const int tid = threadIdx.x;
  const int s   = tid >> 2;  // sample within tile 0..63
  const int cq  = tid & 3;   // c-quarter (16 cols)
  const int rt  = blockIdx.x;
  const float* pb = pw + (size_t)rt * 5 * 4096;

  float h4[4] = {0.f, 0.f, 0.f, 0.f};
#pragma unroll
  for (int cc = 0; cc < 16; ++cc) {
    const int c = cq * 16 + cc;
    const int o = c * 64 + s;
    float p = pb[o];
#pragma unroll
    for (int q = 1; q < 5; ++q) p += pb[q * 4096 + o];  // fixed order
    float hv = fmaxf(p + b1[c], 0.f);
    const float4 w2 = *(const float4*)(W2 + c * 4);
    h4[0] = fmaf(hv, w2.x, h4[0]);
    h4[1] = fmaf(hv, w2.y, h4[1]);
    h4[2] = fmaf(hv, w2.z, h4[2]);
    h4[3] = fmaf(hv, w2.w, h4[3]);
  }
#pragma unroll
  for (int k = 0; k < 4; ++k) {
    h4[k] += __shfl_xor(h4[k], 1);
    h4[k] += __shfl_xor(h4[k], 2);
  }

  float red[4];
#pragma unroll
  for (int k = 0; k < 4; ++k) red[k] = tanhf(h4[k] + b2[k]);

  const float logit = qfc_head(red, qw, Wc1, bc1, Wc2, bc2);
  if (cq == 0) out[rt * 64 + s] = logit;
}

// ============ Fallback: round-1 pure-VALU kernel (no ws needed) ============
#define NKT 20
__global__ __launch_bounds__(256) void qfc_fused(
    const float* __restrict__ x, const float* __restrict__ W1,
    const float* __restrict__ b1, const float* __restrict__ W2,
    const float* __restrict__ b2, const float* __restrict__ qw,
    const float* __restrict__ Wc1, const float* __restrict__ bc1,
    const float* __restrict__ Wc2, const float* __restrict__ bc2,
    float* __restrict__ out) {
  __shared__ float lds[16384];
  const int tid = threadIdx.x;
  const int lane = tid & 63;
  const int wv = tid >> 6;
  const int rg = lane >> 3;
  const int cg = lane & 7;
  const int r0 = blockIdx.x * 64;
  float acc[8][8];
#pragma unroll
  for (int i = 0; i < 8; ++i)
#pragma unroll
    for (int j = 0; j < 8; ++j) acc[i][j] = 0.f;
  const float* xrow = x + (size_t)(r0 + lane) * 1280 + wv * 16;
  const int aBase = wv * 1024;
  const int bBase = 8192 + wv * 1024;
  float4 a_st[4], b_st[4];
  auto issue_loads = [&](int kt) {
    const float* ap = xrow + kt * 64;
#pragma unroll
    for (int i = 0; i < 4; ++i) a_st[i] = *(const float4*)(ap + i * 4);
    const float* bp = W1 + kt * 4096 + wv * 1024 + lane * 4;
#pragma unroll
    for (int i = 0; i < 4; ++i) b_st[i] = *(const float4*)(bp + i * 256);
  };
  auto write_stage = [&](int buf) {
    float* A = &lds[buf * 4096 + aBase];
#pragma unroll
    for (int i = 0; i < 4; ++i) {
      float* p = A + i * 256 + lane;
      p[0] = a_st[i].x; p[64] = a_st[i].y; p[128] = a_st[i].z; p[192] = a_st[i].w;
    }
    float* Bp = &lds[buf * 4096 + bBase + lane * 4];
#pragma unroll
    for (int i = 0; i < 4; ++i) *(float4*)(Bp + i * 256) = b_st[i];
  };
  auto compute_tile = [&](int buf) {
#pragma unroll
    for (int m = 0; m < 16; ++m) {
      const float* Ak = &lds[buf * 4096 + aBase + m * 64];
      const float* Bk = &lds[buf * 4096 + bBase + m * 64];
      const float4 a0 = *(const float4*)(Ak + rg * 8);
      const float4 a1 = *(const float4*)(Ak + rg * 8 + 4);
      const float4 c0 = *(const float4*)(Bk + cg * 8);
      const float4 c1 = *(const float4*)(Bk + cg * 8 + 4);
      const float av[8] = {a0.x, a0.y, a0.z, a0.w, a1.x, a1.y, a1.z, a1.w};
      const float bv[8] = {c0.x, c0.y, c0.z, c0.w, c1.x, c1.y, c1.z, c1.w};
#pragma unroll
      for (int i = 0; i < 8; ++i)
#pragma unroll
        for (int j = 0; j < 8; ++j) acc[i][j] = fmaf(av[i], bv[j], acc[i][j]);
    }
  };
  issue_loads(0);
  write_stage(0);
  for (int kt = 0; kt < NKT; ++kt) {
    const int buf = kt & 1;
    if (kt + 1 < NKT) issue_loads(kt + 1);
    compute_tile(buf);
    if (kt + 1 < NKT) write_stage(buf ^ 1);
  }
  __syncthreads();
#pragma unroll
  for (int j = 0; j < 8; ++j) {
    const int c = cg * 8 + j;
    float* p = &lds[wv * 4096 + c * 64 + rg * 8];
    *(float4*)p = make_float4(acc[0][j], acc[1][j], acc[2][j], acc[3][j]);
    *(float4*)(p + 4) = make_float4(acc[4][j], acc[5][j], acc[6][j], acc[7][j]);
  }
  __syncthreads();
  const int s = tid >> 2;
  const int cq = tid & 3;
  float h4[4] = {0.f, 0.f, 0.f, 0.f};
#pragma unroll
  for (int cc = 0; cc < 16; ++cc) {
    const int c = cq * 16 + cc;
    const int o = c * 64 + s;
    float pp = (lds[o] + lds[4096 + o]) + (lds[8192 + o] + lds[12288 + o]);
    float hv = fmaxf(pp + b1[c], 0.f);
    const float4 w2 = *(const float4*)(W2 + c * 4);
    h4[0] = fmaf(hv, w2.x, h4[0]);
    h4[1] = fmaf(hv, w2.y, h4[1]);
    h4[2] = fmaf(hv, w2.z, h4[2]);
    h4[3] = fmaf(hv, w2.w, h4[3]);
  }
#pragma unroll
  for (int k = 0; k < 4; ++k) {
    h4[k] += __shfl_xor(h4[k], 1);
    h4[k] += __shfl_xor(h4[k], 2);
  }
  float red[4];
#pragma unroll
  for (int k = 0; k < 4; ++k) red[k] = tanhf(h4[k] + b2[k]);
  const float logit = qfc_head(red, qw, Wc1, bc1, Wc2, bc2);
  if (cq == 0) out[r0 + s] = logit;
}

extern "C" void kernel_launch(void* const* d_in, const int* in_sizes, int n_in,
                              void* d_out, int out_size, void* d_ws, size_t ws_size,
                              hipStream_t stream) {
  const float* x   = (const float*)d_in[0];
  const float* W1  = (const float*)d_in[1];
  const float* b1  = (const float*)d_in[2];
  const float* W2  = (const float*)d_in[3];
  const float* b2  = (const float*)d_in[4];
  const float* qw  = (const float*)d_in[5];
  const float* Wc1 = (const float*)d_in[6];
  const float* bc1 = (const float*)d_in[7];
  const float* Wc2 = (const float*)d_in[8];
  const float* bc2 = (const float*)d_in[9];

  const size_t WF_BYTES = 327680;                    // W1 hi/lo frags
  const size_t PW_OFF   = WF_BYTES;
  const size_t PW_BYTES = (size_t)1280 * 4096 * 4;   // 20 MB partials
  if (ws_size >= PW_OFF + PW_BYTES) {
    unsigned short* wf = (unsigned short*)d_ws;
    float* pw = (float*)((char*)d_ws + PW_OFF);
    prep_w1<<<dim3(40), dim3(256), 0, stream>>>(W1, wf);
    qfc_gemm<<<dim3(1280), dim3(256), 0, stream>>>(x, wf, pw);
    qfc_tail<<<dim3(256), dim3(256), 0, stream>>>(
        pw, b1, W2, b2, qw, Wc1, bc1, Wc2, bc2, (float*)d_out);
  } else {
    qfc_fused<<<dim3(256), dim3(256), 0, stream>>>(
        x, W1, b1, W2, b2, qw, Wc1, bc1, Wc2, bc2, (float*)d_out);
  }
}